// Round 14
// baseline (1573.203 us; speedup 1.0000x reference)
//
#include <hip/hip_runtime.h>

// ---------------------------------------------------------------------------
// GinkaBottleneck: transformer(4 layers, T=16, D=512) + GCN + fusion, B=2048.
// R13: consumer-side LayerNorm fold. LN(y)W+b = r(yW') - r*mu*d + c with
// W'=diag(g)W (folded in wconvert), d=gW, c=betaW+b (foldvec kernel). The
// consumer GEMM computes A-row stats from its own MFMA fragments (waves 0,4;
// kg-lanes cover the full row), applies affine in epilogue (OUT=5); residual
// consumers recompute LN from raw y + stats buffer (OUT=6). Eliminates 8 LN
// dispatches; h never materializes (Bp evolves z->y->z in place).
// GEMM core frozen (R10 8-phase, counted vmcnt, 0 bank conflicts).
// ---------------------------------------------------------------------------

typedef _Float16 f16;
typedef f16 f16x8 __attribute__((ext_vector_type(8)));
typedef f16 f16x4 __attribute__((ext_vector_type(4)));
typedef float f32x4 __attribute__((ext_vector_type(4)));

__device__ inline float wred_sum(float s) {
#pragma unroll
  for (int m = 32; m; m >>= 1) s += __shfl_xor(s, m);
  return s;
}

// ---------------- weight convert: f32 [K,N] -> f16 [N,K] (opt row-scale) ----
struct WDesc {
  const float* src;
  const float* gs;  // optional row scale g[k] (LN fold), nullptr = none
  f16* dst;
  int K, N, tiles_n, tile_base, mode;  // mode 0 = transpose, 1 = copy
};
struct WTable {
  WDesc d[32];
  int n;
};

__global__ void wconvert_kernel(WTable tab) {
  const int tile = blockIdx.x;
  int di = 0;
  while (di + 1 < tab.n && tab.d[di + 1].tile_base <= tile) ++di;
  const WDesc w = tab.d[di];
  const int t = tile - w.tile_base;
  const int tk = t / w.tiles_n, tn = t % w.tiles_n;
  const int tid = threadIdx.x;
  const int rr = tid >> 5, cc = tid & 31;
  __shared__ float tb[32][33];
  if (w.mode == 0) {
#pragma unroll
    for (int i = 0; i < 4; i++) {
      const int k = tk * 32 + i * 8 + rr, n = tn * 32 + cc;
      tb[i * 8 + rr][cc] = w.src[(size_t)k * w.N + n];
    }
    __syncthreads();
#pragma unroll
    for (int i = 0; i < 4; i++) {
      const int n = tn * 32 + i * 8 + rr, k = tk * 32 + cc;
      const float gv = w.gs ? w.gs[k] : 1.0f;
      w.dst[(size_t)n * w.K + k] = (f16)(tb[cc][i * 8 + rr] * gv);
    }
  } else {
#pragma unroll
    for (int i = 0; i < 4; i++) {
      const int k = tk * 32 + i * 8 + rr, n = tn * 32 + cc;
      w.dst[(size_t)k * w.N + n] = (f16)w.src[(size_t)k * w.N + n];
    }
  }
}

// ---------------- foldvec: c_n = beta.W + bias, d_n = g.W (K=512) -----------
struct FDesc {
  const float* W;
  const float* g;
  const float* be;
  const float* bias;
  int N, ld, coff, doff, obase;
};
struct FTable {
  FDesc d[16];
  int n;
};

__global__ void foldvec_kernel(FTable tab, float* __restrict__ CD) {
  const int gid = blockIdx.x * 256 + threadIdx.x;
  int di = 0;
  while (di + 1 < tab.n && tab.d[di + 1].obase <= gid) ++di;
  const FDesc f = tab.d[di];
  const int n = gid - f.obase;
  if (n >= f.N) return;
  float c = 0.f, d = 0.f;
  for (int k = 0; k < 512; ++k) {
    const float w = f.W[(size_t)k * f.ld + n];
    c += f.be[k] * w;
    d += f.g[k] * w;
  }
  CD[f.coff + n] = c + f.bias[n];
  CD[f.doff + n] = d;
}

__global__ void biaspack_kernel(const float* __restrict__ bq,
                                const float* __restrict__ bk,
                                const float* __restrict__ bv,
                                float* __restrict__ bqkv) {
  const int i = blockIdx.x * 256 + threadIdx.x;
  if (i >= 4 * 1536) return;
  const int l = i / 1536, j = i % 1536;
  float v;
  if (j < 512)       v = bq[l * 512 + j];
  else if (j < 1024) v = bk[l * 512 + j - 512];
  else               v = bv[l * 512 + j - 1024];
  bqkv[i] = v;
}

// ---------------- prep: x[b,c,t] (f32) -> X0[b*16+t, c] (f16) ---------------
__global__ void prep_kernel(const float* __restrict__ x, f16* __restrict__ X0) {
  const int b = blockIdx.x;
  for (int c = threadIdx.x; c < 512; c += 256) {
    const float* src = x + ((size_t)b * 512 + c) * 16;
    float vals[16];
#pragma unroll
    for (int i = 0; i < 4; i++) {
      const float4 v = ((const float4*)src)[i];
      vals[i * 4 + 0] = v.x; vals[i * 4 + 1] = v.y;
      vals[i * 4 + 2] = v.z; vals[i * 4 + 3] = v.w;
    }
#pragma unroll
    for (int t = 0; t < 16; t++)
      X0[((size_t)b * 16 + t) * 512 + c] = (f16)vals[t];
  }
}

// ---------------- GEMM 256x256, 8-phase: C = A[M,K] * Bt[N,K]^T -------------
// OUT: 0 = f16 (+bias, opt relu); 3 = InstanceNorm16+ELU NCHW f32; 4 = f16 +
// bias + residual(resp); 5 = LN-folded: r*(acc - mu*d) + c (aux1=c, aux2=d,
// own in-loop stats, opt relu); 6 = acc + bias + LN-residual from raw y
// (resp=y, statsIn, aux1=g, aux2=beta). STATS: waves 0,4 accumulate A-row
// sum/sumsq from the MFMA fragments; reduce over kg lanes; write LDS+global.
#define STAGE_SLOT(TI, ISB, HALF)                                              \
  {                                                                            \
    f16* dstb_ = smw + ((TI) & 1) * 32768 + ((ISB) ? 16384 : 0) +              \
                 (HALF) * 8192 + ldsw2;                                        \
    const int ld_ = (ISB) ? ldb : lda;                                         \
    const f16* src_ = ((ISB) ? gBs : gAs) + (size_t)((HALF) * 128) * ld_ +     \
                      ((size_t)(TI) << 6);                                     \
    __builtin_amdgcn_global_load_lds(                                          \
        (const __attribute__((address_space(1))) void*)(src_),                 \
        (__attribute__((address_space(3))) void*)(dstb_), 16, 0, 0);           \
    __builtin_amdgcn_global_load_lds(                                          \
        (const __attribute__((address_space(1))) void*)(src_ + (size_t)64 * ld_), \
        (__attribute__((address_space(3))) void*)(dstb_ + 4096), 16, 0, 0);    \
  }

#define VM4 asm volatile("s_waitcnt vmcnt(4)" ::: "memory");
#define VM0 asm volatile("s_waitcnt vmcnt(0)" ::: "memory");
#define VMN

#define PHASE(TI, P, FIRST, DOSTG, STI, SISB, SHALF, VM)                       \
  {                                                                            \
    const f16* Ab_ = smw + ((TI) & 1) * 32768;                                 \
    const f16* Bb_ = Ab_ + 16384;                                              \
    if (FIRST) {                                                               \
      _Pragma("unroll") for (int n = 0; n < 4; ++n) {                          \
        const int r = wn + n * 16 + rm;                                        \
        bf[n][0] = *(const f16x8*)(Bb_ + r * 64 + koff0);                      \
        bf[n][1] = *(const f16x8*)(Bb_ + r * 64 + koff1);                      \
      }                                                                        \
    }                                                                          \
    const int r0_ = wm + (2 * (P)) * 16 + rm;                                  \
    const f16x8 a0k0 = *(const f16x8*)(Ab_ + r0_ * 64 + koff0);                \
    const f16x8 a0k1 = *(const f16x8*)(Ab_ + r0_ * 64 + koff1);                \
    const f16x8 a1k0 = *(const f16x8*)(Ab_ + (r0_ + 16) * 64 + koff0);         \
    const f16x8 a1k1 = *(const f16x8*)(Ab_ + (r0_ + 16) * 64 + koff1);         \
    if (DOSTG) STAGE_SLOT(STI, SISB, SHALF)                                    \
    VM                                                                         \
    __builtin_amdgcn_s_barrier();                                              \
    asm volatile("s_waitcnt lgkmcnt(0)" ::: "memory");                         \
    __builtin_amdgcn_sched_barrier(0);                                         \
    __builtin_amdgcn_s_setprio(1);                                             \
    _Pragma("unroll") for (int n = 0; n < 4; ++n) {                            \
      acc[2 * (P)][n] = __builtin_amdgcn_mfma_f32_16x16x32_f16(                \
          a0k0, bf[n][0], acc[2 * (P)][n], 0, 0, 0);                           \
      acc[2 * (P)][n] = __builtin_amdgcn_mfma_f32_16x16x32_f16(                \
          a0k1, bf[n][1], acc[2 * (P)][n], 0, 0, 0);                           \
      acc[2 * (P) + 1][n] = __builtin_amdgcn_mfma_f32_16x16x32_f16(            \
          a1k0, bf[n][0], acc[2 * (P) + 1][n], 0, 0, 0);                       \
      acc[2 * (P) + 1][n] = __builtin_amdgcn_mfma_f32_16x16x32_f16(            \
          a1k1, bf[n][1], acc[2 * (P) + 1][n], 0, 0, 0);                       \
    }                                                                          \
    __builtin_amdgcn_s_setprio(0);                                             \
    if (STATS && (wid & 3) == 0) {                                             \
      _Pragma("unroll") for (int e = 0; e < 8; ++e) {                          \
        const float v0_ = (float)a0k0[e], v1_ = (float)a0k1[e];                \
        const float v2_ = (float)a1k0[e], v3_ = (float)a1k1[e];                \
        rs[2 * (P)] += v0_ + v1_;                                              \
        rq[2 * (P)] += v0_ * v0_ + v1_ * v1_;                                  \
        rs[2 * (P) + 1] += v2_ + v3_;                                          \
        rq[2 * (P) + 1] += v2_ * v2_ + v3_ * v3_;                              \
      }                                                                        \
    }                                                                          \
    __builtin_amdgcn_s_barrier();                                              \
    __builtin_amdgcn_sched_barrier(0);                                         \
  }

template <int OUT, bool RELU, bool HASB, int NT, bool STATS>
__global__ __launch_bounds__(512) void gemm256_kernel(
    const f16* __restrict__ A, const f16* __restrict__ Bt, void* __restrict__ C,
    const float* __restrict__ bias, const f16* __restrict__ resp,
    const float* __restrict__ aux1, const float* __restrict__ aux2,
    const float* __restrict__ statsIn, float* __restrict__ statsOut,
    int N, int lda, int ldb) {
  __shared__ alignas(16) f16 smem[65536];  // 128 KiB
  f16* smw = smem;
  const int tid = threadIdx.x;
  const int nb = N >> 8;
  const int cpx = gridDim.x >> 3;  // grid always a multiple of 8
  const int wg = (blockIdx.x & 7) * cpx + (blockIdx.x >> 3);
  const int bx = wg % nb, by = wg / nb;
  const int row0 = by << 8, col0 = bx << 8;
  const int lane = tid & 63;
  const int wid = tid >> 6;
  const int wm = (wid >> 2) << 7;  // 0 / 128
  const int wn = (wid & 3) << 6;   // 0 / 64 / 128 / 192
  const int rm = lane & 15;
  const int kg = lane >> 4;
  const int key = rm & 7;
  const int koff0 = ((kg ^ key)) << 3;
  const int koff1 = (((4 + kg) ^ key)) << 3;
  const int schunk = (tid & 7) ^ ((tid >> 3) & 7);
  const f16* gAs = A + (size_t)(row0 + (tid >> 3)) * lda + (schunk << 3);
  const f16* gBs = Bt + (size_t)(col0 + (tid >> 3)) * ldb + (schunk << 3);
  const int ldsw2 = (tid & 0x1C0) << 3;  // wave*512 elems
  f32x4 acc[8][4] = {};
  f16x8 bf[4][2];
  float rs[8] = {}, rq[8] = {};

  STAGE_SLOT(0, 0, 0)
  STAGE_SLOT(0, 0, 1)
  STAGE_SLOT(0, 1, 0)
  STAGE_SLOT(0, 1, 1)
  STAGE_SLOT(1, 1, 0)
  STAGE_SLOT(1, 1, 1)
  VM4
  __builtin_amdgcn_s_barrier();
  __builtin_amdgcn_sched_barrier(0);

#pragma unroll 1
  for (int j = 0; j < NT / 2 - 1; ++j) {
    const int u = 2 * j, v = u + 1, t2 = u + 2, t3 = u + 3;
    PHASE(u, 0, true,  true, v,  0, 0, VMN)
    PHASE(u, 1, false, true, v,  0, 1, VMN)
    PHASE(u, 2, false, true, t2, 1, 0, VMN)
    PHASE(u, 3, false, true, t2, 1, 1, VM4)
    PHASE(v, 0, true,  true, t2, 0, 0, VMN)
    PHASE(v, 1, false, true, t2, 0, 1, VMN)
    PHASE(v, 2, false, true, t3, 1, 0, VMN)
    PHASE(v, 3, false, true, t3, 1, 1, VM4)
  }
  {  // peeled last iter
    const int u = NT - 2, v = NT - 1;
    PHASE(u, 0, true,  true,  v, 0, 0, VMN)
    PHASE(u, 1, false, true,  v, 0, 1, VMN)
    PHASE(u, 2, false, false, 0, 0, 0, VMN)
    PHASE(u, 3, false, false, 0, 0, 0, VM0)
    PHASE(v, 0, true,  false, 0, 0, 0, VMN)
    PHASE(v, 1, false, false, 0, 0, 0, VMN)
    PHASE(v, 2, false, false, 0, 0, 0, VMN)
    PHASE(v, 3, false, false, 0, 0, 0, VMN)
  }

  const int cn = lane & 15;
  const int rg = (lane >> 4) << 2;
  float* ldsStats = (float*)smw;  // 256 rows x {s,q} = 2 KB (tile reads done)
  if (STATS) {
    if ((wid & 3) == 0) {
#pragma unroll
      for (int p2 = 0; p2 < 8; ++p2) {
        float s = rs[p2], q = rq[p2];
        s += __shfl_xor(s, 16); s += __shfl_xor(s, 32);
        q += __shfl_xor(q, 16); q += __shfl_xor(q, 32);
        if (lane < 16) {
          const int lr = wm + p2 * 16 + lane;
          ldsStats[lr * 2] = s;
          ldsStats[lr * 2 + 1] = q;
          *(float2*)(statsOut + (size_t)(row0 + lr) * 2) = make_float2(s, q);
        }
      }
    }
    __syncthreads();
  }

  if (OUT == 3) {
    // Fused InstanceNorm2d (no affine) + ELU + NCHW float4 write.
    float* out = (float*)C;
#pragma unroll
    for (int m = 0; m < 8; ++m) {
      const int bidx = (row0 >> 4) + (wm >> 4) + m;
#pragma unroll
      for (int n = 0; n < 4; ++n) {
        const int col = col0 + wn + n * 16 + cn;
        const float v0 = acc[m][n][0], v1 = acc[m][n][1];
        const float v2 = acc[m][n][2], v3 = acc[m][n][3];
        float s = v0 + v1 + v2 + v3;
        s += __shfl_xor(s, 16);
        s += __shfl_xor(s, 32);
        const float mu = s * (1.f / 16.f);
        float q = (v0 - mu) * (v0 - mu) + (v1 - mu) * (v1 - mu) +
                  (v2 - mu) * (v2 - mu) + (v3 - mu) * (v3 - mu);
        q += __shfl_xor(q, 16);
        q += __shfl_xor(q, 32);
        const float rstd = rsqrtf(q * (1.f / 16.f) + 1e-5f);
        float4 z;
        z.x = (v0 - mu) * rstd; z.x = z.x > 0.f ? z.x : expm1f(z.x);
        z.y = (v1 - mu) * rstd; z.y = z.y > 0.f ? z.y : expm1f(z.y);
        z.z = (v2 - mu) * rstd; z.z = z.z > 0.f ? z.z : expm1f(z.z);
        z.w = (v3 - mu) * rstd; z.w = z.w > 0.f ? z.w : expm1f(z.w);
        *(float4*)(out + ((size_t)bidx * 512 + col) * 16 + rg) = z;
      }
    }
  } else if (OUT == 5) {
    // v = r*(acc - mu*d[col]) + c[col]  (own stats; aux1=c, aux2=d)
#pragma unroll
    for (int m = 0; m < 8; ++m) {
#pragma unroll
      for (int r = 0; r < 4; ++r) {
        const int lr = wm + m * 16 + rg + r;
        const float mu = ldsStats[lr * 2] * (1.f / 512.f);
        const float rr2 =
            rsqrtf(ldsStats[lr * 2 + 1] * (1.f / 512.f) - mu * mu + 1e-5f);
        const size_t row = (size_t)row0 + lr;
#pragma unroll
        for (int n = 0; n < 4; ++n) {
          const int col = col0 + wn + n * 16 + cn;
          float v = rr2 * (acc[m][n][r] - mu * aux2[col]) + aux1[col];
          if (RELU) v = v > 0.f ? v : 0.f;
          ((f16*)C)[row * N + col] = (f16)v;
        }
      }
    }
  } else if (OUT == 6) {
    // v = acc + bias[col] + (y - mu)*r*g[col] + beta[col]
    // (resp = raw y; statsIn from the stats-GEMM; aux1=g, aux2=beta)
#pragma unroll
    for (int m = 0; m < 8; ++m) {
#pragma unroll
      for (int r = 0; r < 4; ++r) {
        const size_t row = (size_t)row0 + wm + m * 16 + rg + r;
        const float s_ = statsIn[row * 2], q_ = statsIn[row * 2 + 1];
        const float mu = s_ * (1.f / 512.f);
        const float rr2 = rsqrtf(q_ * (1.f / 512.f) - mu * mu + 1e-5f);
#pragma unroll
        for (int n = 0; n < 4; ++n) {
          const int col = col0 + wn + n * 16 + cn;
          const float yv = (float)resp[row * N + col];
          const float v =
              acc[m][n][r] + bias[col] + (yv - mu) * rr2 * aux1[col] + aux2[col];
          ((f16*)C)[row * N + col] = (f16)v;
        }
      }
    }
  } else {
#pragma unroll
    for (int m = 0; m < 8; ++m) {
#pragma unroll
      for (int n = 0; n < 4; ++n) {
        const int col = col0 + wn + n * 16 + cn;
        const float bv = HASB ? bias[col] : 0.0f;
#pragma unroll
        for (int r = 0; r < 4; ++r) {
          const int row = row0 + wm + m * 16 + rg + r;
          float v = acc[m][n][r] + bv;
          if (OUT == 4) v += (float)resp[(size_t)row * N + col];
          if (RELU) v = v > 0.f ? v : 0.f;
          ((f16*)C)[(size_t)row * N + col] = (f16)v;
        }
      }
    }
  }
}

// ---------------- row LayerNorm over D=512 (emb only: +pos) -----------------
template <bool RES, bool POS>
__global__ void ln_kernel(const f16* in, const f16* res, const float* g,
                          const float* b, const float* pos, f16* out) {
  const int row = (blockIdx.x << 2) + (threadIdx.x >> 6);
  const int lane = threadIdx.x & 63;
  const int c0 = lane << 3;
  float v[8];
  const f16x8 xi = *(const f16x8*)(in + (size_t)row * 512 + c0);
  if (RES) {
    const f16x8 ri = *(const f16x8*)(res + (size_t)row * 512 + c0);
#pragma unroll
    for (int j = 0; j < 8; j++) v[j] = (float)xi[j] + (float)ri[j];
  } else {
#pragma unroll
    for (int j = 0; j < 8; j++) v[j] = (float)xi[j];
  }
  float s = 0;
#pragma unroll
  for (int j = 0; j < 8; j++) s += v[j];
  s = wred_sum(s);
  const float mu = s * (1.f / 512.f);
  float q = 0;
#pragma unroll
  for (int j = 0; j < 8; j++) {
    const float d = v[j] - mu;
    q += d * d;
  }
  q = wred_sum(q);
  const float rstd = rsqrtf(q * (1.f / 512.f) + 1e-5f);
  const int t = row & 15;
  f16x8 o8;
#pragma unroll
  for (int j = 0; j < 8; j++) {
    float o = (v[j] - mu) * rstd * g[c0 + j] + b[c0 + j];
    if (POS) o += pos[t * 512 + c0 + j];
    o8[j] = (f16)o;
  }
  *(f16x8*)(out + (size_t)row * 512 + c0) = o8;
}

// ---------------- lnpack: F[:, :512] = LN(fc_out); F[:, 512:] = X2 ----------
__global__ void lnpack_kernel(const f16* __restrict__ in, const f16* __restrict__ x2,
                              const float* __restrict__ g, const float* __restrict__ b,
                              f16* __restrict__ F) {
  const int row = (blockIdx.x << 2) + (threadIdx.x >> 6);
  const int lane = threadIdx.x & 63;
  const int c0 = lane << 3;
  const f16x8 xi = *(const f16x8*)(in + (size_t)row * 512 + c0);
  float v[8];
#pragma unroll
  for (int j = 0; j < 8; j++) v[j] = (float)xi[j];
  float s = 0;
#pragma unroll
  for (int j = 0; j < 8; j++) s += v[j];
  s = wred_sum(s);
  const float mu = s * (1.f / 512.f);
  float q = 0;
#pragma unroll
  for (int j = 0; j < 8; j++) {
    const float d = v[j] - mu;
    q += d * d;
  }
  q = wred_sum(q);
  const float rstd = rsqrtf(q * (1.f / 512.f) + 1e-5f);
  f16x8 o8;
#pragma unroll
  for (int j = 0; j < 8; j++)
    o8[j] = (f16)((v[j] - mu) * rstd * g[c0 + j] + b[c0 + j]);
  *(f16x8*)(F + (size_t)row * 1024 + c0) = o8;
  const f16x8 x2v = *(const f16x8*)(x2 + (size_t)row * 512 + c0);
  *(f16x8*)(F + (size_t)row * 1024 + 512 + c0) = x2v;
}

// ---------------- attention: MFMA, one (b,head) per wave, 4 waves/block -----
__global__ __launch_bounds__(256) void attn_kernel(const f16* __restrict__ qkv,
                                                   f16* __restrict__ o) {
  __shared__ f16 smem[4][3776];  // per wave: Q[16][72] K[16][72] V[16][72] P[16][20]
  const int wid = threadIdx.x >> 6;
  const int lane = threadIdx.x & 63;
  const int bh = (blockIdx.x << 2) + wid;
  const int b = bh >> 3, h = bh & 7;
  f16* W = smem[wid];
  f16* Qw = W;
  f16* Kw = W + 1152;
  f16* Vw = W + 2304;
  f16* Pw = W + 3456;
  const size_t base = (size_t)b * 24576 + (size_t)h * 64;
#pragma unroll
  for (int i = 0; i < 6; i++) {
    const int c = i * 64 + lane;
    const int t = c / 24;
    const int rem = c - t * 24;
    const int mat = rem >> 3, ch = rem & 7;
    const f16x8 v = *(const f16x8*)(qkv + base + (size_t)t * 1536 + mat * 512 + ch * 8);
    *(f16x8*)(W + mat * 1152 + t * 72 + ch * 8) = v;
  }
  __syncthreads();
  const int rm = lane & 15, kg = lane >> 4;
  f32x4 s4 = {};
  {
    const f16x8 q0 = *(const f16x8*)(Qw + rm * 72 + kg * 8);
    const f16x8 q1 = *(const f16x8*)(Qw + rm * 72 + 32 + kg * 8);
    const f16x8 k0 = *(const f16x8*)(Kw + rm * 72 + kg * 8);
    const f16x8 k1 = *(const f16x8*)(Kw + rm * 72 + 32 + kg * 8);
    s4 = __builtin_amdgcn_mfma_f32_16x16x32_f16(q0, k0, s4, 0, 0, 0);
    s4 = __builtin_amdgcn_mfma_f32_16x16x32_f16(q1, k1, s4, 0, 0, 0);
  }
  float p[4];
#pragma unroll
  for (int r = 0; r < 4; r++) {
    const float sv = s4[r] * 0.125f;
    float m = sv;
    m = fmaxf(m, __shfl_xor(m, 1));
    m = fmaxf(m, __shfl_xor(m, 2));
    m = fmaxf(m, __shfl_xor(m, 4));
    m = fmaxf(m, __shfl_xor(m, 8));
    const float e = expf(sv - m);
    float s = e;
    s += __shfl_xor(s, 1);
    s += __shfl_xor(s, 2);
    s += __shfl_xor(s, 4);
    s += __shfl_xor(s, 8);
    p[r] = e / s;
  }
#pragma unroll
  for (int r = 0; r < 4; r++) Pw[(kg * 4 + r) * 20 + rm] = (f16)p[r];
  __syncthreads();
  const f16x4 pa = *(const f16x4*)(Pw + rm * 20 + kg * 4);
  f32x4 o4[4] = {};
#pragma unroll
  for (int dt = 0; dt < 4; dt++) {
    f16x4 vb;
#pragma unroll
    for (int kk = 0; kk < 4; kk++) vb[kk] = Vw[(kg * 4 + kk) * 72 + dt * 16 + rm];
    o4[dt] = __builtin_amdgcn_mfma_f32_16x16x16f16(pa, vb, o4[dt], 0, 0, 0);
  }
  f16* op = o + (size_t)b * 16 * 512 + (size_t)h * 64;
#pragma unroll
  for (int dt = 0; dt < 4; dt++)
#pragma unroll
    for (int r = 0; r < 4; r++)
      op[(size_t)(kg * 4 + r) * 512 + dt * 16 + rm] = (f16)o4[dt][r];
}

// ---------------- GCN adj-mix + bias + LN + ELU (one block per b) -----------
template <int DG>
__global__ __launch_bounds__(256) void adjmix_kernel(
    const f16* __restrict__ r, const float* __restrict__ adj,
    const float* __restrict__ bias, const float* __restrict__ g,
    const float* __restrict__ bet, f16* __restrict__ out, int ldo) {
  const int b = blockIdx.x;
  const int tid = threadIdx.x;
  __shared__ float agg[16][DG];
  __shared__ float adjs[256];
  if (tid < 256) adjs[tid] = adj[tid];
  __syncthreads();
  const int d0 = tid * 4;
  if (d0 < DG) {
    float acc[16][4];
#pragma unroll
    for (int m = 0; m < 16; m++)
#pragma unroll
      for (int j = 0; j < 4; j++) acc[m][j] = 0.f;
#pragma unroll
    for (int n = 0; n < 16; n++) {
      const f16x4 v = *(const f16x4*)(r + ((size_t)b * 16 + n) * DG + d0);
      const float v0 = (float)v[0], v1 = (float)v[1], v2 = (float)v[2], v3 = (float)v[3];
#pragma unroll
      for (int m = 0; m < 16; m++) {
        const float a = adjs[m * 16 + n];
        acc[m][0] += a * v0;
        acc[m][1] += a * v1;
        acc[m][2] += a * v2;
        acc[m][3] += a * v3;
      }
    }
    const float4 bv = *(const float4*)(bias + d0);
#pragma unroll
    for (int m = 0; m < 16; m++) {
      agg[m][d0 + 0] = acc[m][0] + bv.x;
      agg[m][d0 + 1] = acc[m][1] + bv.y;
      agg[m][d0 + 2] = acc[m][2] + bv.z;
      agg[m][d0 + 3] = acc[m][3] + bv.w;
    }
  }
  __syncthreads();
  const int wave = tid >> 6, lane = tid & 63;
  for (int m = wave; m < 16; m += 4) {
    float s = 0;
#pragma unroll
    for (int j = 0; j < DG / 64; j++) s += agg[m][j * 64 + lane];
    s = wred_sum(s);
    const float mu = s / DG;
    float q = 0;
#pragma unroll
    for (int j = 0; j < DG / 64; j++) {
      const float t = agg[m][j * 64 + lane] - mu;
      q += t * t;
    }
    q = wred_sum(q);
    const float rstd = rsqrtf(q / DG + 1e-5f);
    const size_t grow = (size_t)b * 16 + m;
#pragma unroll
    for (int j = 0; j < DG / 64; j++) {
      const int d = j * 64 + lane;
      float v = (agg[m][d] - mu) * rstd * g[d] + bet[d];
      v = v > 0.f ? v : expm1f(v);
      out[grow * ldo + d] = (f16)v;
    }
  }
}

// ---------------------------------------------------------------------------
extern "C" void kernel_launch(void* const* d_in, const int* in_sizes, int n_in,
                              void* d_out, int out_size, void* d_ws, size_t ws_size,
                              hipStream_t stream) {
  (void)in_sizes; (void)n_in; (void)out_size; (void)ws_size;
  const float* x         = (const float*)d_in[0];
  const float* emb_w     = (const float*)d_in[1];
  const float* emb_b     = (const float*)d_in[2];
  const float* emb_ln_g  = (const float*)d_in[3];
  const float* emb_ln_b  = (const float*)d_in[4];
  const float* pos       = (const float*)d_in[5];
  const float* attn_wq   = (const float*)d_in[6];
  const float* attn_wk   = (const float*)d_in[7];
  const float* attn_wv   = (const float*)d_in[8];
  const float* attn_bq   = (const float*)d_in[9];
  const float* attn_bk   = (const float*)d_in[10];
  const float* attn_bv   = (const float*)d_in[11];
  const float* attn_wo   = (const float*)d_in[12];
  const float* attn_bo   = (const float*)d_in[13];
  const float* ln1_g     = (const float*)d_in[14];
  const float* ln1_b     = (const float*)d_in[15];
  const float* ff_w1     = (const float*)d_in[16];
  const float* ff_b1     = (const float*)d_in[17];
  const float* ff_w2     = (const float*)d_in[18];
  const float* ff_b2     = (const float*)d_in[19];
  const float* ln2_g     = (const float*)d_in[20];
  const float* ln2_b     = (const float*)d_in[21];
  const float* fc_w      = (const float*)d_in[22];
  const float* fc_b      = (const float*)d_in[23];
  const float* fc_ln_g   = (const float*)d_in[24];
  const float* fc_ln_b   = (const float*)d_in[25];
  const float* gcn_w1    = (const float*)d_in[26];
  const float* gcn_b1    = (const float*)d_in[27];
  const float* gcn_ln1_g = (const float*)d_in[28];
  const float* gcn_ln1_b = (const float*)d_in[29];
  const float* gcn_w2    = (const float*)d_in[30];
  const float* gcn_b2    = (const float*)d_in[31];
  const float* gcn_ln2_g = (const float*)d_in[32];
  const float* gcn_ln2_b = (const float*)d_in[33];
  const float* fusion_w  = (const float*)d_in[34];
  const float* fusion_b  = (const float*)d_in[35];
  const float* adj       = (const float*)d_in[36];
  (void)fusion_b;  // cancels under instance norm

  // ---- workspace map (bytes); peak ~212.6 MiB ----
  char* ws = (char*)d_ws;
  f16*   WF   = (f16*)(ws);                      // 20,971,520 B of weights
  float* BQKV = (float*)(ws + 20971520ull);      //     24,576 B
  f16*   Ap   = (f16*)(ws + 20996096ull);        // 32 MiB  (X0, then X2)
  f16*   Bp   = (f16*)(ws + 54550528ull);        // 32 MiB  (h0 -> y/z in place)
  f16*   Cp   = (f16*)(ws + 88104960ull);        // 32 MiB  (attn O scratch)
  f16*   Qp   = (f16*)(ws + 121659392ull);       // 96 MiB  (qkv / ff scratch)
  float* S1   = (float*)(ws + 222322688ull);     // 256 KiB row stats (z)
  float* S2   = (float*)(ws + 222584832ull);     // 256 KiB row stats (y)
  float* CD   = (float*)(ws + 222846976ull);     // 73,728 B fold vectors

  // WF layout (f16 element offsets)
  const size_t o_emb = 0, o_qkv = 262144, o_wo = 3407872, o_ff1 = 4456448,
               o_ff2 = 6553600, o_fc = 8650752, o_g1 = 8912896, o_g2 = 9437184,
               o_fus = 9961472;

  WTable tab{};
  int ntab = 0, tbase = 0;
  auto add = [&](const float* s, const float* gs, f16* dst, int K, int N, int mode) {
    WDesc& w = tab.d[ntab++];
    w.src = s; w.gs = gs; w.dst = dst; w.K = K; w.N = N;
    w.tiles_n = N / 32; w.tile_base = tbase; w.mode = mode;
    tbase += (K / 32) * (N / 32);
  };
  add(emb_w, nullptr, WF + o_emb, 512, 512, 0);
  for (int l = 0; l < 4; l++) {
    const float* gs = (l >= 1) ? (ln2_g + (l - 1) * 512) : nullptr;
    add(attn_wq + l * 262144, gs, WF + o_qkv + (size_t)l * 786432, 512, 512, 0);
    add(attn_wk + l * 262144, gs, WF + o_qkv + (size_t)l * 786432 + 262144, 512, 512, 0);
    add(attn_wv + l * 262144, gs, WF + o_qkv + (size_t)l * 786432 + 524288, 512, 512, 0);
  }
  for (int l = 0; l < 4; l++)
    add(attn_wo + l * 262144, nullptr, WF + o_wo + (size_t)l * 262144, 512, 512, 0);
  for (int l = 0; l < 4; l++)
    add(ff_w1 + l * 524288, ln1_g + l * 512, WF + o_ff1 + (size_t)l * 524288, 512, 1024, 0);
  for (int l = 0; l < 4; l++)
    add(ff_w2 + l * 524288, nullptr, WF + o_ff2 + (size_t)l * 524288, 1024, 512, 0);
  add(fc_w, ln2_g + 3 * 512, WF + o_fc, 512, 512, 0);
  add(gcn_w1, nullptr, WF + o_g1, 512, 1024, 0);
  add(gcn_w2, nullptr, WF + o_g2, 1024, 512, 0);
  add(fusion_w, nullptr, WF + o_fus, 512, 1024, 1);
  tab.n = ntab;

  // fold-vector table: c = beta.W + bias, d = g.W
  FTable ft{};
  int nf = 0, ob = 0;
  auto fadd = [&](const float* W, const float* g, const float* be,
                  const float* bias, int N, int ld, int coff, int doff) {
    FDesc& f = ft.d[nf++];
    f.W = W; f.g = g; f.be = be; f.bias = bias;
    f.N = N; f.ld = ld; f.coff = coff; f.doff = doff; f.obase = ob;
    ob += N;
  };
  // CD layout (f32): ff1 [c1024|d1024] x4 @0; qkv [c1536|d1536] x3 @8192;
  // fc [c512|d512] @17408.
  for (int l = 0; l < 4; l++)
    fadd(ff_w1 + l * 524288, ln1_g + l * 512, ln1_b + l * 512,
         ff_b1 + l * 1024, 1024, 1024, l * 2048, l * 2048 + 1024);
  for (int l = 1; l < 4; l++) {
    const int c0 = 8192 + (l - 1) * 3072, d0 = c0 + 1536;
    fadd(attn_wq + l * 262144, ln2_g + (l - 1) * 512, ln2_b + (l - 1) * 512,
         attn_bq + l * 512, 512, 512, c0 + 0, d0 + 0);
    fadd(attn_wk + l * 262144, ln2_g + (l - 1) * 512, ln2_b + (l - 1) * 512,
         attn_bk + l * 512, 512, 512, c0 + 512, d0 + 512);
    fadd(attn_wv + l * 262144, ln2_g + (l - 1) * 512, ln2_b + (l - 1) * 512,
         attn_bv + l * 512, 512, 512, c0 + 1024, d0 + 1024);
  }
  fadd(fc_w, ln2_g + 3 * 512, ln2_b + 3 * 512, fc_b, 512, 512, 17408, 17920);
  ft.n = nf;

  wconvert_kernel<<<tbase, 256, 0, stream>>>(tab);
  biaspack_kernel<<<24, 256, 0, stream>>>(attn_bq, attn_bk, attn_bv, BQKV);
  foldvec_kernel<<<36, 256, 0, stream>>>(ft, CD);
  prep_kernel<<<2048, 256, 0, stream>>>(x, Ap);  // X0 in A

  // ---- GCN branch ----
  gemm256_kernel<0, false, false, 8, false><<<512, 512, 0, stream>>>(
      Ap, WF + o_g1, Qp, nullptr, nullptr, nullptr, nullptr, nullptr, nullptr,
      1024, 512, 512);
  adjmix_kernel<1024><<<2048, 256, 0, stream>>>(
      Qp, adj, gcn_b1, gcn_ln1_g, gcn_ln1_b, Bp, 1024);
  gemm256_kernel<0, false, false, 16, false><<<256, 512, 0, stream>>>(
      Bp, WF + o_g2, Qp, nullptr, nullptr, nullptr, nullptr, nullptr, nullptr,
      512, 1024, 1024);

  // ---- transformer embed + LN + pos -> h0 in Bp ----
  gemm256_kernel<0, false, true, 8, false><<<256, 512, 0, stream>>>(
      Ap, WF + o_emb, Cp, emb_b, nullptr, nullptr, nullptr, nullptr, nullptr,
      512, 512, 512);
  ln_kernel<false, true><<<8192, 256, 0, stream>>>(
      Cp, nullptr, emb_ln_g, emb_ln_b, pos, Bp);

  // GCN adjmix2 -> X2 in A
  adjmix_kernel<512><<<2048, 256, 0, stream>>>(
      Qp, adj, gcn_b2, gcn_ln2_g, gcn_ln2_b, Ap, 512);

  // ---- transformer layers ----
  for (int i = 0; i < 4; i++) {
    if (i == 0) {
      // QKV_0: plain (A = h0), bias packed
      gemm256_kernel<0, false, true, 8, false><<<768, 512, 0, stream>>>(
          Bp, WF + o_qkv, Qp, BQKV, nullptr, nullptr, nullptr, nullptr, nullptr,
          1536, 512, 512);
    } else {
      // QKV_i: LN2-folded (A = z_{i-1} raw), own stats -> S1
      const int c0 = 8192 + (i - 1) * 3072;
      gemm256_kernel<5, false, false, 8, true><<<768, 512, 0, stream>>>(
          Bp, WF + o_qkv + (size_t)i * 786432, Qp, nullptr, nullptr,
          CD + c0, CD + c0 + 1536, nullptr, S1, 1536, 512, 512);
    }
    attn_kernel<<<4096, 256, 0, stream>>>(Qp, Cp);
    if (i == 0) {
      // WO_0: + residual h0 (plain), in-place Bp -> y_0
      gemm256_kernel<4, false, true, 8, false><<<256, 512, 0, stream>>>(
          Cp, WF + o_wo, Bp, attn_bo, Bp, nullptr, nullptr, nullptr, nullptr,
          512, 512, 512);
    } else {
      // WO_i: + LN2(z_{i-1}) residual from raw z (Bp) + S1 stats; in-place -> y_i
      gemm256_kernel<6, false, true, 8, false><<<256, 512, 0, stream>>>(
          Cp, WF + o_wo + (size_t)i * 262144, Bp, attn_bo + i * 512, Bp,
          ln2_g + (i - 1) * 512, ln2_b + (i - 1) * 512, S1, nullptr,
          512, 512, 512);
    }
    // FF1_i: LN1-folded (A = y_i raw), relu, stats -> S2
    gemm256_kernel<5, true, false, 8, true><<<512, 512, 0, stream>>>(
        Bp, WF + o_ff1 + (size_t)i * 524288, Qp, nullptr, nullptr,
        CD + i * 2048, CD + i * 2048 + 1024, nullptr, S2, 1024, 512, 512);
    // FF2_i: + LN1(y_i) residual from raw y (Bp) + S2 stats; in-place -> z_i
    gemm256_kernel<6, false, true, 16, false><<<256, 512, 0, stream>>>(
        Qp, WF + o_ff2 + (size_t)i * 524288, Bp, ff_b2 + i * 512, Bp,
        ln1_g + i * 512, ln1_b + i * 512, S2, nullptr, 512, 1024, 1024);
  }

  // ---- fc: LN2_3-folded (A = z_3 raw), own stats -> Qp ----
  gemm256_kernel<5, false, false, 8, true><<<256, 512, 0, stream>>>(
      Bp, WF + o_fc, Qp, nullptr, nullptr, CD + 17408, CD + 17920, nullptr, S1,
      512, 512, 512);
  lnpack_kernel<<<8192, 256, 0, stream>>>(Qp, Ap, fc_ln_g, fc_ln_b, Bp);

  // ---- fusion GEMM K=1024 with fused InstanceNorm+ELU+NCHW epilogue ----
  gemm256_kernel<3, false, false, 16, false><<<256, 512, 0, stream>>>(
      Bp, WF + o_fus, d_out, nullptr, nullptr, nullptr, nullptr, nullptr,
      nullptr, 512, 1024, 1024);
}

// Round 15
// 1290.699 us; speedup vs baseline: 1.2189x; 1.2189x over previous
//
#include <hip/hip_runtime.h>

// ---------------------------------------------------------------------------
// GinkaBottleneck: transformer(4 layers, T=16, D=512) + GCN + fusion, B=2048.
// R14: revert to R12 (best measured: 1287 us, verified twice). 8-phase
// gemm256 (BK=64, 2 dbuf x 2 half LDS, counted vmcnt(4) at ph4/8, both-sides
// row&7 swizzle, setprio) + residual-fused WO/FF2 epilogues (OUT=4) +
// standalone LN + fused InstanceNorm fusion-GEMM tail.
// R13's consumer-side LN fold regressed (in-loop stats on waves 0/4 extend
// every wave's barrier-lockstep critical path: QKV 69->129us) and is removed.
// ---------------------------------------------------------------------------

typedef _Float16 f16;
typedef f16 f16x8 __attribute__((ext_vector_type(8)));
typedef f16 f16x4 __attribute__((ext_vector_type(4)));
typedef float f32x4 __attribute__((ext_vector_type(4)));

__device__ inline float wred_sum(float s) {
#pragma unroll
  for (int m = 32; m; m >>= 1) s += __shfl_xor(s, m);
  return s;
}

// ---------------- weight convert: f32 [K,N] -> f16 [N,K] (or copy) ----------
struct WDesc {
  const float* src;
  f16* dst;
  int K, N, tiles_n, tile_base, mode;  // mode 0 = transpose, 1 = copy
};
struct WTable {
  WDesc d[32];
  int n;
};

__global__ void wconvert_kernel(WTable tab) {
  const int tile = blockIdx.x;
  int di = 0;
  while (di + 1 < tab.n && tab.d[di + 1].tile_base <= tile) ++di;
  const WDesc w = tab.d[di];
  const int t = tile - w.tile_base;
  const int tk = t / w.tiles_n, tn = t % w.tiles_n;
  const int tid = threadIdx.x;
  const int rr = tid >> 5, cc = tid & 31;
  __shared__ float tb[32][33];
  if (w.mode == 0) {
#pragma unroll
    for (int i = 0; i < 4; i++) {
      const int k = tk * 32 + i * 8 + rr, n = tn * 32 + cc;
      tb[i * 8 + rr][cc] = w.src[(size_t)k * w.N + n];
    }
    __syncthreads();
#pragma unroll
    for (int i = 0; i < 4; i++) {
      const int n = tn * 32 + i * 8 + rr, k = tk * 32 + cc;
      w.dst[(size_t)n * w.K + k] = (f16)tb[cc][i * 8 + rr];
    }
  } else {
#pragma unroll
    for (int i = 0; i < 4; i++) {
      const int k = tk * 32 + i * 8 + rr, n = tn * 32 + cc;
      w.dst[(size_t)k * w.N + n] = (f16)w.src[(size_t)k * w.N + n];
    }
  }
}

__global__ void biaspack_kernel(const float* __restrict__ bq,
                                const float* __restrict__ bk,
                                const float* __restrict__ bv,
                                float* __restrict__ bqkv) {
  const int i = blockIdx.x * 256 + threadIdx.x;
  if (i >= 4 * 1536) return;
  const int l = i / 1536, j = i % 1536;
  float v;
  if (j < 512)       v = bq[l * 512 + j];
  else if (j < 1024) v = bk[l * 512 + j - 512];
  else               v = bv[l * 512 + j - 1024];
  bqkv[i] = v;
}

// ---------------- prep: x[b,c,t] (f32) -> X0[b*16+t, c] (f16) ---------------
__global__ void prep_kernel(const float* __restrict__ x, f16* __restrict__ X0) {
  const int b = blockIdx.x;
  for (int c = threadIdx.x; c < 512; c += 256) {
    const float* src = x + ((size_t)b * 512 + c) * 16;
    float vals[16];
#pragma unroll
    for (int i = 0; i < 4; i++) {
      const float4 v = ((const float4*)src)[i];
      vals[i * 4 + 0] = v.x; vals[i * 4 + 1] = v.y;
      vals[i * 4 + 2] = v.z; vals[i * 4 + 3] = v.w;
    }
#pragma unroll
    for (int t = 0; t < 16; t++)
      X0[((size_t)b * 16 + t) * 512 + c] = (f16)vals[t];
  }
}

// ---------------- GEMM 256x256, 8-phase: C = A[M,K] * Bt[N,K]^T -------------
// 8 waves (2Mx4N), per-wave C 128x64, BK=64, NT = K/64 K-tiles.
// LDS: dbuf d = tile&1: A[256][64] @ d*32768, B[256][64] @ +16384 (f16 elems).
// OUT: 0 = f16 (+bias, opt relu); 3 = InstanceNorm16+ELU NCHW f32; 4 = f16 +
// bias + residual.
#define STAGE_SLOT(TI, ISB, HALF)                                              \
  {                                                                            \
    f16* dstb_ = smw + ((TI) & 1) * 32768 + ((ISB) ? 16384 : 0) +              \
                 (HALF) * 8192 + ldsw2;                                        \
    const int ld_ = (ISB) ? ldb : lda;                                         \
    const f16* src_ = ((ISB) ? gBs : gAs) + (size_t)((HALF) * 128) * ld_ +     \
                      ((size_t)(TI) << 6);                                     \
    __builtin_amdgcn_global_load_lds(                                          \
        (const __attribute__((address_space(1))) void*)(src_),                 \
        (__attribute__((address_space(3))) void*)(dstb_), 16, 0, 0);           \
    __builtin_amdgcn_global_load_lds(                                          \
        (const __attribute__((address_space(1))) void*)(src_ + (size_t)64 * ld_), \
        (__attribute__((address_space(3))) void*)(dstb_ + 4096), 16, 0, 0);    \
  }

#define VM4 asm volatile("s_waitcnt vmcnt(4)" ::: "memory");
#define VM0 asm volatile("s_waitcnt vmcnt(0)" ::: "memory");
#define VMN

#define PHASE(TI, P, FIRST, DOSTG, STI, SISB, SHALF, VM)                       \
  {                                                                            \
    const f16* Ab_ = smw + ((TI) & 1) * 32768;                                 \
    const f16* Bb_ = Ab_ + 16384;                                              \
    if (FIRST) {                                                               \
      _Pragma("unroll") for (int n = 0; n < 4; ++n) {                          \
        const int r = wn + n * 16 + rm;                                        \
        bf[n][0] = *(const f16x8*)(Bb_ + r * 64 + koff0);                      \
        bf[n][1] = *(const f16x8*)(Bb_ + r * 64 + koff1);                      \
      }                                                                        \
    }                                                                          \
    const int r0_ = wm + (2 * (P)) * 16 + rm;                                  \
    const f16x8 a0k0 = *(const f16x8*)(Ab_ + r0_ * 64 + koff0);                \
    const f16x8 a0k1 = *(const f16x8*)(Ab_ + r0_ * 64 + koff1);                \
    const f16x8 a1k0 = *(const f16x8*)(Ab_ + (r0_ + 16) * 64 + koff0);         \
    const f16x8 a1k1 = *(const f16x8*)(Ab_ + (r0_ + 16) * 64 + koff1);         \
    if (DOSTG) STAGE_SLOT(STI, SISB, SHALF)                                    \
    VM                                                                         \
    __builtin_amdgcn_s_barrier();                                              \
    asm volatile("s_waitcnt lgkmcnt(0)" ::: "memory");                         \
    __builtin_amdgcn_sched_barrier(0);                                         \
    __builtin_amdgcn_s_setprio(1);                                             \
    _Pragma("unroll") for (int n = 0; n < 4; ++n) {                            \
      acc[2 * (P)][n] = __builtin_amdgcn_mfma_f32_16x16x32_f16(                \
          a0k0, bf[n][0], acc[2 * (P)][n], 0, 0, 0);                           \
      acc[2 * (P)][n] = __builtin_amdgcn_mfma_f32_16x16x32_f16(                \
          a0k1, bf[n][1], acc[2 * (P)][n], 0, 0, 0);                           \
      acc[2 * (P) + 1][n] = __builtin_amdgcn_mfma_f32_16x16x32_f16(            \
          a1k0, bf[n][0], acc[2 * (P) + 1][n], 0, 0, 0);                       \
      acc[2 * (P) + 1][n] = __builtin_amdgcn_mfma_f32_16x16x32_f16(            \
          a1k1, bf[n][1], acc[2 * (P) + 1][n], 0, 0, 0);                       \
    }                                                                          \
    __builtin_amdgcn_s_setprio(0);                                             \
    __builtin_amdgcn_s_barrier();                                              \
    __builtin_amdgcn_sched_barrier(0);                                         \
  }

template <int OUT, bool RELU, bool HASB, int NT>
__global__ __launch_bounds__(512) void gemm256_kernel(
    const f16* __restrict__ A, const f16* __restrict__ Bt, void* __restrict__ C,
    const float* __restrict__ bias, const f16* __restrict__ resp,
    int N, int lda, int ldb) {
  __shared__ alignas(16) f16 smem[65536];  // 128 KiB
  f16* smw = smem;
  const int tid = threadIdx.x;
  const int nb = N >> 8;
  const int cpx = gridDim.x >> 3;  // grid always a multiple of 8
  const int wg = (blockIdx.x & 7) * cpx + (blockIdx.x >> 3);
  const int bx = wg % nb, by = wg / nb;
  const int row0 = by << 8, col0 = bx << 8;
  const int lane = tid & 63;
  const int wid = tid >> 6;
  const int wm = (wid >> 2) << 7;  // 0 / 128
  const int wn = (wid & 3) << 6;   // 0 / 64 / 128 / 192
  const int rm = lane & 15;
  const int kg = lane >> 4;
  const int key = rm & 7;
  const int koff0 = ((kg ^ key)) << 3;
  const int koff1 = (((4 + kg) ^ key)) << 3;
  const int schunk = (tid & 7) ^ ((tid >> 3) & 7);
  const f16* gAs = A + (size_t)(row0 + (tid >> 3)) * lda + (schunk << 3);
  const f16* gBs = Bt + (size_t)(col0 + (tid >> 3)) * ldb + (schunk << 3);
  const int ldsw2 = (tid & 0x1C0) << 3;  // wave*512 elems
  f32x4 acc[8][4] = {};
  f16x8 bf[4][2];

  STAGE_SLOT(0, 0, 0)
  STAGE_SLOT(0, 0, 1)
  STAGE_SLOT(0, 1, 0)
  STAGE_SLOT(0, 1, 1)
  STAGE_SLOT(1, 1, 0)
  STAGE_SLOT(1, 1, 1)
  VM4
  __builtin_amdgcn_s_barrier();
  __builtin_amdgcn_sched_barrier(0);

#pragma unroll 1
  for (int j = 0; j < NT / 2 - 1; ++j) {
    const int u = 2 * j, v = u + 1, t2 = u + 2, t3 = u + 3;
    PHASE(u, 0, true,  true, v,  0, 0, VMN)
    PHASE(u, 1, false, true, v,  0, 1, VMN)
    PHASE(u, 2, false, true, t2, 1, 0, VMN)
    PHASE(u, 3, false, true, t2, 1, 1, VM4)
    PHASE(v, 0, true,  true, t2, 0, 0, VMN)
    PHASE(v, 1, false, true, t2, 0, 1, VMN)
    PHASE(v, 2, false, true, t3, 1, 0, VMN)
    PHASE(v, 3, false, true, t3, 1, 1, VM4)
  }
  {  // peeled last iter: only v.A stages remain; vmcnt(0) before reading v.
    const int u = NT - 2, v = NT - 1;
    PHASE(u, 0, true,  true,  v, 0, 0, VMN)
    PHASE(u, 1, false, true,  v, 0, 1, VMN)
    PHASE(u, 2, false, false, 0, 0, 0, VMN)
    PHASE(u, 3, false, false, 0, 0, 0, VM0)
    PHASE(v, 0, true,  false, 0, 0, 0, VMN)
    PHASE(v, 1, false, false, 0, 0, 0, VMN)
    PHASE(v, 2, false, false, 0, 0, 0, VMN)
    PHASE(v, 3, false, false, 0, 0, 0, VMN)
  }

  const int cn = lane & 15;
  const int rg = (lane >> 4) << 2;
  if (OUT == 3) {
    // Fused InstanceNorm2d (no affine) + ELU + NCHW float4 write.
    float* out = (float*)C;
#pragma unroll
    for (int m = 0; m < 8; ++m) {
      const int bidx = (row0 >> 4) + (wm >> 4) + m;
#pragma unroll
      for (int n = 0; n < 4; ++n) {
        const int col = col0 + wn + n * 16 + cn;
        const float v0 = acc[m][n][0], v1 = acc[m][n][1];
        const float v2 = acc[m][n][2], v3 = acc[m][n][3];
        float s = v0 + v1 + v2 + v3;
        s += __shfl_xor(s, 16);
        s += __shfl_xor(s, 32);
        const float mu = s * (1.f / 16.f);
        float q = (v0 - mu) * (v0 - mu) + (v1 - mu) * (v1 - mu) +
                  (v2 - mu) * (v2 - mu) + (v3 - mu) * (v3 - mu);
        q += __shfl_xor(q, 16);
        q += __shfl_xor(q, 32);
        const float rstd = rsqrtf(q * (1.f / 16.f) + 1e-5f);
        float4 z;
        z.x = (v0 - mu) * rstd; z.x = z.x > 0.f ? z.x : expm1f(z.x);
        z.y = (v1 - mu) * rstd; z.y = z.y > 0.f ? z.y : expm1f(z.y);
        z.z = (v2 - mu) * rstd; z.z = z.z > 0.f ? z.z : expm1f(z.z);
        z.w = (v3 - mu) * rstd; z.w = z.w > 0.f ? z.w : expm1f(z.w);
        *(float4*)(out + ((size_t)bidx * 512 + col) * 16 + rg) = z;
      }
    }
  } else {
#pragma unroll
    for (int m = 0; m < 8; ++m) {
#pragma unroll
      for (int n = 0; n < 4; ++n) {
        const int col = col0 + wn + n * 16 + cn;
        const float bv = HASB ? bias[col] : 0.0f;
#pragma unroll
        for (int r = 0; r < 4; ++r) {
          const int row = row0 + wm + m * 16 + rg + r;
          float v = acc[m][n][r] + bv;
          if (OUT == 4) v += (float)resp[(size_t)row * N + col];
          if (RELU) v = v > 0.f ? v : 0.f;
          ((f16*)C)[(size_t)row * N + col] = (f16)v;
        }
      }
    }
  }
}

// ---------------- row LayerNorm over D=512 ----------------------------------
template <bool RES, bool POS>
__global__ void ln_kernel(const f16* in, const f16* res, const float* g,
                          const float* b, const float* pos, f16* out) {
  const int row = (blockIdx.x << 2) + (threadIdx.x >> 6);
  const int lane = threadIdx.x & 63;
  const int c0 = lane << 3;
  float v[8];
  const f16x8 xi = *(const f16x8*)(in + (size_t)row * 512 + c0);
  if (RES) {
    const f16x8 ri = *(const f16x8*)(res + (size_t)row * 512 + c0);
#pragma unroll
    for (int j = 0; j < 8; j++) v[j] = (float)xi[j] + (float)ri[j];
  } else {
#pragma unroll
    for (int j = 0; j < 8; j++) v[j] = (float)xi[j];
  }
  float s = 0;
#pragma unroll
  for (int j = 0; j < 8; j++) s += v[j];
  s = wred_sum(s);
  const float mu = s * (1.f / 512.f);
  float q = 0;
#pragma unroll
  for (int j = 0; j < 8; j++) {
    const float d = v[j] - mu;
    q += d * d;
  }
  q = wred_sum(q);
  const float rstd = rsqrtf(q * (1.f / 512.f) + 1e-5f);
  const int t = row & 15;
  f16x8 o8;
#pragma unroll
  for (int j = 0; j < 8; j++) {
    float o = (v[j] - mu) * rstd * g[c0 + j] + b[c0 + j];
    if (POS) o += pos[t * 512 + c0 + j];
    o8[j] = (f16)o;
  }
  *(f16x8*)(out + (size_t)row * 512 + c0) = o8;
}

// ---------------- lnpack: F[:, :512] = LN(fc_out); F[:, 512:] = X2 ----------
__global__ void lnpack_kernel(const f16* __restrict__ in, const f16* __restrict__ x2,
                              const float* __restrict__ g, const float* __restrict__ b,
                              f16* __restrict__ F) {
  const int row = (blockIdx.x << 2) + (threadIdx.x >> 6);
  const int lane = threadIdx.x & 63;
  const int c0 = lane << 3;
  const f16x8 xi = *(const f16x8*)(in + (size_t)row * 512 + c0);
  float v[8];
#pragma unroll
  for (int j = 0; j < 8; j++) v[j] = (float)xi[j];
  float s = 0;
#pragma unroll
  for (int j = 0; j < 8; j++) s += v[j];
  s = wred_sum(s);
  const float mu = s * (1.f / 512.f);
  float q = 0;
#pragma unroll
  for (int j = 0; j < 8; j++) {
    const float d = v[j] - mu;
    q += d * d;
  }
  q = wred_sum(q);
  const float rstd = rsqrtf(q * (1.f / 512.f) + 1e-5f);
  f16x8 o8;
#pragma unroll
  for (int j = 0; j < 8; j++)
    o8[j] = (f16)((v[j] - mu) * rstd * g[c0 + j] + b[c0 + j]);
  *(f16x8*)(F + (size_t)row * 1024 + c0) = o8;
  const f16x8 x2v = *(const f16x8*)(x2 + (size_t)row * 512 + c0);
  *(f16x8*)(F + (size_t)row * 1024 + 512 + c0) = x2v;
}

// ---------------- attention: MFMA, one (b,head) per wave, 4 waves/block -----
__global__ __launch_bounds__(256) void attn_kernel(const f16* __restrict__ qkv,
                                                   f16* __restrict__ o) {
  __shared__ f16 smem[4][3776];  // per wave: Q[16][72] K[16][72] V[16][72] P[16][20]
  const int wid = threadIdx.x >> 6;
  const int lane = threadIdx.x & 63;
  const int bh = (blockIdx.x << 2) + wid;
  const int b = bh >> 3, h = bh & 7;
  f16* W = smem[wid];
  f16* Qw = W;
  f16* Kw = W + 1152;
  f16* Vw = W + 2304;
  f16* Pw = W + 3456;
  const size_t base = (size_t)b * 24576 + (size_t)h * 64;
#pragma unroll
  for (int i = 0; i < 6; i++) {
    const int c = i * 64 + lane;
    const int t = c / 24;
    const int rem = c - t * 24;
    const int mat = rem >> 3, ch = rem & 7;
    const f16x8 v = *(const f16x8*)(qkv + base + (size_t)t * 1536 + mat * 512 + ch * 8);
    *(f16x8*)(W + mat * 1152 + t * 72 + ch * 8) = v;
  }
  __syncthreads();
  const int rm = lane & 15, kg = lane >> 4;
  f32x4 s4 = {};
  {
    const f16x8 q0 = *(const f16x8*)(Qw + rm * 72 + kg * 8);
    const f16x8 q1 = *(const f16x8*)(Qw + rm * 72 + 32 + kg * 8);
    const f16x8 k0 = *(const f16x8*)(Kw + rm * 72 + kg * 8);
    const f16x8 k1 = *(const f16x8*)(Kw + rm * 72 + 32 + kg * 8);
    s4 = __builtin_amdgcn_mfma_f32_16x16x32_f16(q0, k0, s4, 0, 0, 0);
    s4 = __builtin_amdgcn_mfma_f32_16x16x32_f16(q1, k1, s4, 0, 0, 0);
  }
  float p[4];
#pragma unroll
  for (int r = 0; r < 4; r++) {
    const float sv = s4[r] * 0.125f;
    float m = sv;
    m = fmaxf(m, __shfl_xor(m, 1));
    m = fmaxf(m, __shfl_xor(m, 2));
    m = fmaxf(m, __shfl_xor(m, 4));
    m = fmaxf(m, __shfl_xor(m, 8));
    const float e = expf(sv - m);
    float s = e;
    s += __shfl_xor(s, 1);
    s += __shfl_xor(s, 2);
    s += __shfl_xor(s, 4);
    s += __shfl_xor(s, 8);
    p[r] = e / s;
  }
#pragma unroll
  for (int r = 0; r < 4; r++) Pw[(kg * 4 + r) * 20 + rm] = (f16)p[r];
  __syncthreads();
  const f16x4 pa = *(const f16x4*)(Pw + rm * 20 + kg * 4);
  f32x4 o4[4] = {};
#pragma unroll
  for (int dt = 0; dt < 4; dt++) {
    f16x4 vb;
#pragma unroll
    for (int kk = 0; kk < 4; kk++) vb[kk] = Vw[(kg * 4 + kk) * 72 + dt * 16 + rm];
    o4[dt] = __builtin_amdgcn_mfma_f32_16x16x16f16(pa, vb, o4[dt], 0, 0, 0);
  }
  f16* op = o + (size_t)b * 16 * 512 + (size_t)h * 64;
#pragma unroll
  for (int dt = 0; dt < 4; dt++)
#pragma unroll
    for (int r = 0; r < 4; r++)
      op[(size_t)(kg * 4 + r) * 512 + dt * 16 + rm] = (f16)o4[dt][r];
}

// ---------------- GCN adj-mix + bias + LN + ELU (one block per b) -----------
template <int DG>
__global__ __launch_bounds__(256) void adjmix_kernel(
    const f16* __restrict__ r, const float* __restrict__ adj,
    const float* __restrict__ bias, const float* __restrict__ g,
    const float* __restrict__ bet, f16* __restrict__ out, int ldo) {
  const int b = blockIdx.x;
  const int tid = threadIdx.x;
  __shared__ float agg[16][DG];
  __shared__ float adjs[256];
  if (tid < 256) adjs[tid] = adj[tid];
  __syncthreads();
  const int d0 = tid * 4;
  if (d0 < DG) {
    float acc[16][4];
#pragma unroll
    for (int m = 0; m < 16; m++)
#pragma unroll
      for (int j = 0; j < 4; j++) acc[m][j] = 0.f;
#pragma unroll
    for (int n = 0; n < 16; n++) {
      const f16x4 v = *(const f16x4*)(r + ((size_t)b * 16 + n) * DG + d0);
      const float v0 = (float)v[0], v1 = (float)v[1], v2 = (float)v[2], v3 = (float)v[3];
#pragma unroll
      for (int m = 0; m < 16; m++) {
        const float a = adjs[m * 16 + n];
        acc[m][0] += a * v0;
        acc[m][1] += a * v1;
        acc[m][2] += a * v2;
        acc[m][3] += a * v3;
      }
    }
    const float4 bv = *(const float4*)(bias + d0);
#pragma unroll
    for (int m = 0; m < 16; m++) {
      agg[m][d0 + 0] = acc[m][0] + bv.x;
      agg[m][d0 + 1] = acc[m][1] + bv.y;
      agg[m][d0 + 2] = acc[m][2] + bv.z;
      agg[m][d0 + 3] = acc[m][3] + bv.w;
    }
  }
  __syncthreads();
  const int wave = tid >> 6, lane = tid & 63;
  for (int m = wave; m < 16; m += 4) {
    float s = 0;
#pragma unroll
    for (int j = 0; j < DG / 64; j++) s += agg[m][j * 64 + lane];
    s = wred_sum(s);
    const float mu = s / DG;
    float q = 0;
#pragma unroll
    for (int j = 0; j < DG / 64; j++) {
      const float t = agg[m][j * 64 + lane] - mu;
      q += t * t;
    }
    q = wred_sum(q);
    const float rstd = rsqrtf(q / DG + 1e-5f);
    const size_t grow = (size_t)b * 16 + m;
#pragma unroll
    for (int j = 0; j < DG / 64; j++) {
      const int d = j * 64 + lane;
      float v = (agg[m][d] - mu) * rstd * g[d] + bet[d];
      v = v > 0.f ? v : expm1f(v);
      out[grow * ldo + d] = (f16)v;
    }
  }
}

// ---------------------------------------------------------------------------
extern "C" void kernel_launch(void* const* d_in, const int* in_sizes, int n_in,
                              void* d_out, int out_size, void* d_ws, size_t ws_size,
                              hipStream_t stream) {
  (void)in_sizes; (void)n_in; (void)out_size; (void)ws_size;
  const float* x         = (const float*)d_in[0];
  const float* emb_w     = (const float*)d_in[1];
  const float* emb_b     = (const float*)d_in[2];
  const float* emb_ln_g  = (const float*)d_in[3];
  const float* emb_ln_b  = (const float*)d_in[4];
  const float* pos       = (const float*)d_in[5];
  const float* attn_wq   = (const float*)d_in[6];
  const float* attn_wk   = (const float*)d_in[7];
  const float* attn_wv   = (const float*)d_in[8];
  const float* attn_bq   = (const float*)d_in[9];
  const float* attn_bk   = (const float*)d_in[10];
  const float* attn_bv   = (const float*)d_in[11];
  const float* attn_wo   = (const float*)d_in[12];
  const float* attn_bo   = (const float*)d_in[13];
  const float* ln1_g     = (const float*)d_in[14];
  const float* ln1_b     = (const float*)d_in[15];
  const float* ff_w1     = (const float*)d_in[16];
  const float* ff_b1     = (const float*)d_in[17];
  const float* ff_w2     = (const float*)d_in[18];
  const float* ff_b2     = (const float*)d_in[19];
  const float* ln2_g     = (const float*)d_in[20];
  const float* ln2_b     = (const float*)d_in[21];
  const float* fc_w      = (const float*)d_in[22];
  const float* fc_b      = (const float*)d_in[23];
  const float* fc_ln_g   = (const float*)d_in[24];
  const float* fc_ln_b   = (const float*)d_in[25];
  const float* gcn_w1    = (const float*)d_in[26];
  const float* gcn_b1    = (const float*)d_in[27];
  const float* gcn_ln1_g = (const float*)d_in[28];
  const float* gcn_ln1_b = (const float*)d_in[29];
  const float* gcn_w2    = (const float*)d_in[30];
  const float* gcn_b2    = (const float*)d_in[31];
  const float* gcn_ln2_g = (const float*)d_in[32];
  const float* gcn_ln2_b = (const float*)d_in[33];
  const float* fusion_w  = (const float*)d_in[34];
  const float* fusion_b  = (const float*)d_in[35];
  const float* adj       = (const float*)d_in[36];
  (void)fusion_b;  // cancels under instance norm

  // ---- workspace map (bytes); peak ~212 MiB ----
  char* ws = (char*)d_ws;
  f16*   WF   = (f16*)(ws);                      // 20,971,520 B of weights
  float* BQKV = (float*)(ws + 20971520ull);      //     24,576 B
  f16*   Ap   = (f16*)(ws + 20996096ull);        // 32 MiB  (X0, then X2)
  f16*   Bp   = (f16*)(ws + 54550528ull);        // 32 MiB  (h; B..C = 64 MiB F)
  f16*   Cp   = (f16*)(ws + 88104960ull);        // 32 MiB  (scratch)
  f16*   Qp   = (f16*)(ws + 121659392ull);       // 96 MiB  (qkv / ff scratch)

  // WF layout (f16 element offsets)
  const size_t o_emb = 0, o_qkv = 262144, o_wo = 3407872, o_ff1 = 4456448,
               o_ff2 = 6553600, o_fc = 8650752, o_g1 = 8912896, o_g2 = 9437184,
               o_fus = 9961472;

  WTable tab{};
  int ntab = 0, tbase = 0;
  auto add = [&](const float* s, f16* dst, int K, int N, int mode) {
    WDesc& w = tab.d[ntab++];
    w.src = s; w.dst = dst; w.K = K; w.N = N;
    w.tiles_n = N / 32; w.tile_base = tbase; w.mode = mode;
    tbase += (K / 32) * (N / 32);
  };
  add(emb_w, WF + o_emb, 512, 512, 0);
  for (int l = 0; l < 4; l++) {
    add(attn_wq + l * 262144, WF + o_qkv + (size_t)l * 786432, 512, 512, 0);
    add(attn_wk + l * 262144, WF + o_qkv + (size_t)l * 786432 + 262144, 512, 512, 0);
    add(attn_wv + l * 262144, WF + o_qkv + (size_t)l * 786432 + 524288, 512, 512, 0);
  }
  for (int l = 0; l < 4; l++)
    add(attn_wo + l * 262144, WF + o_wo + (size_t)l * 262144, 512, 512, 0);
  for (int l = 0; l < 4; l++)
    add(ff_w1 + l * 524288, WF + o_ff1 + (size_t)l * 524288, 512, 1024, 0);
  for (int l = 0; l < 4; l++)
    add(ff_w2 + l * 524288, WF + o_ff2 + (size_t)l * 524288, 1024, 512, 0);
  add(fc_w, WF + o_fc, 512, 512, 0);
  add(gcn_w1, WF + o_g1, 512, 1024, 0);
  add(gcn_w2, WF + o_g2, 1024, 512, 0);
  add(fusion_w, WF + o_fus, 512, 1024, 1);  // already [N,K]: straight copy
  tab.n = ntab;

  wconvert_kernel<<<tbase, 256, 0, stream>>>(tab);
  biaspack_kernel<<<24, 256, 0, stream>>>(attn_bq, attn_bk, attn_bv, BQKV);
  prep_kernel<<<2048, 256, 0, stream>>>(x, Ap);  // X0 in A

  // ---- GCN branch ----
  gemm256_kernel<0, false, false, 8><<<512, 512, 0, stream>>>(
      Ap, WF + o_g1, Qp, nullptr, nullptr, 1024, 512, 512);
  adjmix_kernel<1024><<<2048, 256, 0, stream>>>(
      Qp, adj, gcn_b1, gcn_ln1_g, gcn_ln1_b, Bp, 1024);
  gemm256_kernel<0, false, false, 16><<<256, 512, 0, stream>>>(
      Bp, WF + o_g2, Qp, nullptr, nullptr, 512, 1024, 1024);

  // ---- transformer embed (frees A for X2) ----
  gemm256_kernel<0, false, true, 8><<<256, 512, 0, stream>>>(
      Ap, WF + o_emb, Cp, emb_b, nullptr, 512, 512, 512);
  ln_kernel<false, true><<<8192, 256, 0, stream>>>(
      Cp, nullptr, emb_ln_g, emb_ln_b, pos, Bp);  // h in B

  // GCN adjmix2 -> X2 in A (A free now)
  adjmix_kernel<512><<<2048, 256, 0, stream>>>(
      Qp, adj, gcn_b2, gcn_ln2_g, gcn_ln2_b, Ap, 512);

  // ---- transformer layers (h=B, scratch=C, Q free) ----
  for (int i = 0; i < 4; i++) {
    gemm256_kernel<0, false, true, 8><<<768, 512, 0, stream>>>(
        Bp, WF + o_qkv + (size_t)i * 786432, Qp, BQKV + i * 1536, nullptr,
        1536, 512, 512);
    attn_kernel<<<4096, 256, 0, stream>>>(Qp, Cp);
    // WO GEMM with fused residual (+h) -> Qp
    gemm256_kernel<4, false, true, 8><<<256, 512, 0, stream>>>(
        Cp, WF + o_wo + (size_t)i * 262144, Qp, attn_bo + i * 512, Bp,
        512, 512, 512);
    ln_kernel<false, false><<<8192, 256, 0, stream>>>(
        Qp, nullptr, ln1_g + i * 512, ln1_b + i * 512, nullptr, Bp);
    gemm256_kernel<0, true, true, 8><<<512, 512, 0, stream>>>(
        Bp, WF + o_ff1 + (size_t)i * 524288, Qp, ff_b1 + i * 1024, nullptr,
        1024, 512, 512);
    // FF2 GEMM with fused residual (+h) -> Qp+33M
    gemm256_kernel<4, false, true, 16><<<256, 512, 0, stream>>>(
        Qp, WF + o_ff2 + (size_t)i * 524288, Qp + 33554432ull, ff_b2 + i * 512,
        Bp, 512, 1024, 1024);
    ln_kernel<false, false><<<8192, 256, 0, stream>>>(
        Qp + 33554432ull, nullptr, ln2_g + i * 512, ln2_b + i * 512, nullptr, Bp);
  }

  // ---- fc -> Qp; lnpack: F[:, :512]=LN(Qp), F[:, 512:]=X2 (F = Bp..Cp) ----
  gemm256_kernel<0, false, true, 8><<<256, 512, 0, stream>>>(
      Bp, WF + o_fc, Qp, fc_b, nullptr, 512, 512, 512);
  lnpack_kernel<<<8192, 256, 0, stream>>>(Qp, Ap, fc_ln_g, fc_ln_b, Bp);

  // ---- fusion GEMM K=1024 with fused InstanceNorm+ELU+NCHW epilogue ----
  gemm256_kernel<3, false, false, 16><<<256, 512, 0, stream>>>(
      Bp, WF + o_fus, d_out, nullptr, nullptr, 512, 1024, 1024);
}